// Round 4
// baseline (2521.672 us; speedup 1.0000x reference)
//
#include <hip/hip_runtime.h>
#include <cstdint>
#include <cstddef>
#include <math.h>

#define NANCH    36864
#define NPRE     12000
#define NPRE_PAD 12032
#define NW       188
#define SORT_N   16384
#define NPOST    2000

// triangle base for chunk-pair (ci, cj>=ci): slot = tribase(ci) + (cj-ci)
__device__ __forceinline__ int tribase(int ci) { return ci * NW - (ci * (ci - 1)) / 2; }

// ---------------------------------------------------------------------------
// K1: 3x3 conv (1024->512, 64x64, SAME) + bias + leaky_relu(0.01)
// f64 accumulate (required: np reference is float64; ordering must match).
// 512 blocks (8 oc-tiles x 64 rows) x 256 thr; tile 64oc x 64px (1 row),
// micro 4oc x 4px. LDS 49.9KB -> 2-3 independent blocks/CU so barrier drain
// of one block overlaps FMA issue of another (R3: 1 block/CU, VALUBusy 51%).
// ---------------------------------------------------------------------------
__global__ __launch_bounds__(256, 3)
void k_conv(const float* __restrict__ xg, const float* __restrict__ wg_,
            const float* __restrict__ bg, float* __restrict__ hg)
{
    __shared__ float wlds[144 * 64];     // [ic*9+k][oc]  36 KB
    __shared__ float xlds[16 * 3 * 68];  // [ic][srow][col] 13 KB
    const int tid = threadIdx.x;
    const int oct = blockIdx.x & 7;
    const int y   = blockIdx.x >> 3;     // 0..63
    const int oc0 = oct << 6;
    const int ocg = tid >> 4;            // 0..15 -> 4 oc each
    const int cx0 = (tid & 15) << 2;     // 0..60 col base (4 px each)
    const int lane = tid & 63, wv = tid >> 6;

    double acc[4][4];
#pragma unroll
    for (int o = 0; o < 4; ++o)
#pragma unroll
        for (int j = 0; j < 4; ++j) acc[o][j] = 0.0;

    const float* wbase = wg_ + (size_t)(oc0 + lane) * 9216 + wv;
    float wreg[36], xreg[13];

    // prologue: load chunk 0 into registers
    {
#pragma unroll
        for (int t = 0; t < 36; ++t) wreg[t] = wbase[4 * t];
#pragma unroll
        for (int t = 0; t < 13; ++t) {
            int f = tid + 256 * t; float v = 0.f;
            if (f < 3168) {
                int ic = f / 198; int r = f - ic * 198; int srow = r / 66; int gc = r - srow * 66;
                int gy = y + srow - 1; int gx = gc - 1;
                if (gy >= 0 && gy < 64 && gx >= 0 && gx < 64)
                    v = xg[(size_t)ic * 4096 + gy * 64 + gx];
            }
            xreg[t] = v;
        }
    }

    for (int kc = 0; kc < 64; ++kc) {
        __syncthreads();
        // stage registers -> LDS
#pragma unroll
        for (int t = 0; t < 36; ++t) wlds[(wv + 4 * t) * 64 + lane] = wreg[t];
#pragma unroll
        for (int t = 0; t < 13; ++t) {
            int f = tid + 256 * t;
            if (f < 3168) {
                int ic = f / 198; int r = f - ic * 198; int srow = r / 66; int gc = r - srow * 66;
                xlds[(ic * 3 + srow) * 68 + gc] = xreg[t];
            }
        }
        // prefetch next chunk
        if (kc < 63) {
            const int ic0 = (kc + 1) << 4;
#pragma unroll
            for (int t = 0; t < 36; ++t) wreg[t] = wbase[ic0 * 9 + 4 * t];
#pragma unroll
            for (int t = 0; t < 13; ++t) {
                int f = tid + 256 * t; float v = 0.f;
                if (f < 3168) {
                    int ic = f / 198; int r = f - ic * 198; int srow = r / 66; int gc = r - srow * 66;
                    int gy = y + srow - 1; int gx = gc - 1;
                    if (gy >= 0 && gy < 64 && gx >= 0 && gx < 64)
                        v = xg[(size_t)(ic0 + ic) * 4096 + gy * 64 + gx];
                }
                xreg[t] = v;
            }
        }
        __syncthreads();
        // compute (f64 accumulate)
#pragma unroll 1
        for (int ic = 0; ic < 16; ++ic) {
#pragma unroll
            for (int ky = 0; ky < 3; ++ky) {
                const float* xr = &xlds[(ic * 3 + ky) * 68 + cx0];
                float4 t0 = *(const float4*)(xr);
                float2 t1 = *(const float2*)(xr + 4);
                double xwd[6] = {t0.x, t0.y, t0.z, t0.w, t1.x, t1.y};
#pragma unroll
                for (int kx = 0; kx < 3; ++kx) {
                    const float4 wq = *(const float4*)&wlds[(ic * 9 + ky * 3 + kx) * 64 + (ocg << 2)];
                    double wdv[4] = {wq.x, wq.y, wq.z, wq.w};
#pragma unroll
                    for (int o = 0; o < 4; ++o)
#pragma unroll
                        for (int j = 0; j < 4; ++j)
                            acc[o][j] = fma(wdv[o], xwd[j + kx], acc[o][j]);
                }
            }
        }
    }
    // epilogue: bias + leaky relu (f64), cast to f32, vectorized store
#pragma unroll
    for (int o = 0; o < 4; ++o) {
        const int oc = oc0 + (ocg << 2) + o;
        const double bo = (double)bg[oc];
        float* hp = hg + (size_t)oc * 4096 + y * 64 + cx0;
        float v[4];
#pragma unroll
        for (int j = 0; j < 4; ++j) {
            double t = acc[o][j] + bo;
            v[j] = (float)((t >= 0.0) ? t : 0.01 * t);
        }
        *(float4*)(hp) = make_float4(v[0], v[1], v[2], v[3]);
    }
}

// ---------------------------------------------------------------------------
// K2: 1x1 convs (f64 accumulate) + f64 sort keys + anchors + f32 box deparam
// 64 blocks (one per image row), 256 threads. (passed R3 — unchanged)
// ---------------------------------------------------------------------------
__global__ __launch_bounds__(256, 1)
void k_heads(const float* __restrict__ hg, const float* __restrict__ loc_w,
             const float* __restrict__ loc_b, const float* __restrict__ score_w,
             const float* __restrict__ score_b, const int* __restrict__ imh,
             const int* __restrict__ imw, float* __restrict__ out,
             float* __restrict__ boxes_all, unsigned long long* __restrict__ keys64)
{
    __shared__ float  hch[64 * 64];   // [c][px] chunk of h
    __shared__ float  wch[54 * 64];   // [ch][c] chunk of weights
    __shared__ float  ol[54 * 64];    // [ch][px] f32 outputs
    __shared__ double sld[18 * 64];   // [score ch][px] f64 logits
    const int y = blockIdx.x, tid = threadIdx.x;
    const int px = tid & 63, cg = tid >> 6;
    double acc[14];
#pragma unroll
    for (int u = 0; u < 14; ++u) acc[u] = 0.0;

    for (int cc = 0; cc < 8; ++cc) {
        __syncthreads();
#pragma unroll
        for (int t = 0; t < 16; ++t) {
            int f = tid + 256 * t;
            hch[f] = hg[(size_t)(cc * 64 + (f >> 6)) * 4096 + y * 64 + (f & 63)];
        }
#pragma unroll
        for (int t = 0; t < 14; ++t) {
            int f = tid + 256 * t;
            if (f < 54 * 64) {
                int ch = f >> 6, c = f & 63;
                wch[f] = (ch < 36) ? loc_w[ch * 512 + cc * 64 + c]
                                   : score_w[(ch - 36) * 512 + cc * 64 + c];
            }
        }
        __syncthreads();
        for (int c = 0; c < 64; ++c) {
            double hvd = (double)hch[c * 64 + px];
#pragma unroll
            for (int u = 0; u < 14; ++u) {
                int ch = cg + 4 * u;
                if (ch < 54) acc[u] = fma((double)wch[ch * 64 + c], hvd, acc[u]);
            }
        }
    }
    __syncthreads();
#pragma unroll
    for (int u = 0; u < 14; ++u) {
        int ch = cg + 4 * u;
        if (ch < 54) {
            double s = acc[u] + (double)((ch < 36) ? loc_b[ch] : score_b[ch - 36]);
            ol[ch * 64 + px] = (float)s;
            if (ch >= 36) sld[(ch - 36) * 64 + px] = s;
        }
    }
    __syncthreads();
    for (int f = tid; f < 64 * 36; f += 256) {
        int p = f / 36, ch = f - 36 * p;
        out[(size_t)(y * 64 + p) * 36 + ch] = ol[ch * 64 + p];
    }
    for (int f = tid; f < 64 * 18; f += 256) {
        int p = f / 18, ch = f - 18 * p;
        out[147456 + (size_t)(y * 64 + p) * 18 + ch] = ol[(36 + ch) * 64 + p];
    }
    const float fy = (float)(*imh), fx = (float)(*imw);
    float* anch = out + 229184;
    for (int t2 = tid; t2 < 576; t2 += 256) {
        int p = t2 / 9, a = t2 - 9 * p;
        int pg = y * 64 + p;
        int ar = a / 3, as = a - 3 * ar;
        double rr = (ar == 0) ? 0.5 : ((ar == 1) ? 1.0 : 2.0);
        double ss = (as == 0) ? 8.0 : ((as == 1) ? 16.0 : 32.0);
        double hh = 16.0 * ss * sqrt(rr), wwd = 16.0 * ss * sqrt(1.0 / rr);
        float by1 = (float)(8.0 - hh * 0.5), bx1 = (float)(8.0 - wwd * 0.5);
        float by2 = (float)(8.0 + hh * 0.5), bx2 = (float)(8.0 + wwd * 0.5);
        float sy = (float)(y * 16), sx = (float)(p * 16);
        float a0 = sy + by1, a1 = sx + bx1, a2 = sy + by2, a3 = sx + bx2;
        int base = (pg * 9 + a) * 4;
        anch[base + 0] = a0; anch[base + 1] = a1; anch[base + 2] = a2; anch[base + 3] = a3;
        double d = sld[(a * 2 + 1) * 64 + p] - sld[(a * 2) * 64 + p];
        long long bits = __double_as_longlong(d);
        unsigned long long u64 =
            (unsigned long long)(bits ^ ((bits >> 63) | (long long)0x8000000000000000LL));
        unsigned long long v = ~u64;  // ascending v == descending fg
        keys64[pg * 9 + a] = (v & 0xFFFFFFFFFFFF0000ULL) | (unsigned long long)(pg * 9 + a);
        float dy = ol[(a * 4 + 0) * 64 + p], dxv = ol[(a * 4 + 1) * 64 + p];
        float dh = ol[(a * 4 + 2) * 64 + p], dwv = ol[(a * 4 + 3) * 64 + p];
        float hA = a2 - a0, wA = a3 - a1;
        float cya = a0 + 0.5f * hA, cxa = a1 + 0.5f * wA;
        float cy = dy * hA + cya, cx = dxv * wA + cxa;
        float hb = hA * expf(dh), wb = wA * expf(dwv);
        float b0 = fminf(fmaxf(cy - 0.5f * hb, 0.f), fy);
        float b1 = fminf(fmaxf(cx - 0.5f * wb, 0.f), fx);
        float b2 = fminf(fmaxf(cy + 0.5f * hb, 0.f), fy);
        float b3 = fminf(fmaxf(cx + 0.5f * wb, 0.f), fx);
        boxes_all[base + 0] = b0; boxes_all[base + 1] = b1;
        boxes_all[base + 2] = b2; boxes_all[base + 3] = b3;
    }
}

// ---------------------------------------------------------------------------
// K3: radix-select 12000 smallest keys, compact, bitonic sort with 32KB-LDS
// tiles (4096 u64): only 3 of 105 stages touch global. Single block, 1024 thr.
// ---------------------------------------------------------------------------
__global__ __launch_bounds__(1024, 1)
void k_select(const unsigned long long* __restrict__ keys64,
              const float* __restrict__ boxes_all,
              unsigned long long* __restrict__ sortbuf, float* __restrict__ sbox,
              float* __restrict__ areas, unsigned long long* __restrict__ suppr)
{
    __shared__ unsigned int hist[256];
    __shared__ unsigned int sh_below, sh_prefix, sh_nsel;
    __shared__ unsigned long long tile[4096];   // 32 KB
    const int tid = threadIdx.x;
    if (tid == 0) { sh_below = 0; sh_prefix = 0; sh_nsel = 0; }
    __syncthreads();
    for (int p = 3; p >= 0; --p) {
        if (tid < 256) hist[tid] = 0;
        __syncthreads();
        unsigned int pref = sh_prefix;
        int shift = p * 8;
        for (int i = tid; i < NANCH; i += 1024) {
            unsigned int k = (unsigned int)(keys64[i] >> 32);
            bool match = (p == 3) || ((k >> (shift + 8)) == pref);
            if (match) atomicAdd(&hist[(k >> shift) & 255u], 1u);
        }
        __syncthreads();
        if (tid == 0) {
            unsigned int below = sh_below, cacc = 0;
            int b = 0;
            for (; b < 256; ++b) {
                if (below + cacc + hist[b] >= NPRE) break;
                cacc += hist[b];
            }
            if (b > 255) b = 255;
            sh_below = below + cacc;
            sh_prefix = (pref << 8) | (unsigned int)b;
        }
        __syncthreads();
    }
    const unsigned int P = sh_prefix;
    for (int i = tid; i < NANCH; i += 1024) {
        unsigned long long k = keys64[i];
        if ((unsigned int)(k >> 32) <= P) {
            unsigned int pos = atomicAdd(&sh_nsel, 1u);
            if (pos < SORT_N) sortbuf[pos] = k;
        }
    }
    __syncthreads();
    unsigned int nsel = sh_nsel; if (nsel > SORT_N) nsel = SORT_N;
    for (unsigned int i = nsel + tid; i < SORT_N; i += 1024) sortbuf[i] = ~0ULL;
    __syncthreads();

    // ---- bitonic sort, LDS-tiled ----
    // phase A: k2 = 2..4096 entirely within 4096-elem tiles
    for (int T = 0; T < 4; ++T) {
        for (int t = tid; t < 4096; t += 1024) tile[t] = sortbuf[T * 4096 + t];
        __syncthreads();
        for (int k2 = 2; k2 <= 4096; k2 <<= 1) {
            for (int j = k2 >> 1; j > 0; j >>= 1) {
                for (int t = tid; t < 2048; t += 1024) {
                    int i = ((t & ~(j - 1)) << 1) | (t & (j - 1));
                    int ip = i | j;
                    bool up = (((T * 4096 + i) & k2) == 0);
                    unsigned long long A = tile[i], B = tile[ip];
                    if ((A > B) == up) { tile[i] = B; tile[ip] = A; }
                }
                __syncthreads();
            }
        }
        for (int t = tid; t < 4096; t += 1024) sortbuf[T * 4096 + t] = tile[t];
        __syncthreads();
    }
    // global stage helper
    auto gstage = [&](int k2, int j) {
        for (int t = tid; t < 8192; t += 1024) {
            int i = ((t & ~(j - 1)) << 1) | (t & (j - 1));
            int ip = i | j;
            bool up = ((i & k2) == 0);
            unsigned long long A = sortbuf[i], B = sortbuf[ip];
            if ((A > B) == up) { sortbuf[i] = B; sortbuf[ip] = A; }
        }
        __syncthreads();
    };
    // LDS tail (j <= 2048) for a given k2
    auto ltail = [&](int k2) {
        for (int T = 0; T < 4; ++T) {
            for (int t = tid; t < 4096; t += 1024) tile[t] = sortbuf[T * 4096 + t];
            __syncthreads();
            for (int j = 2048; j > 0; j >>= 1) {
                for (int t = tid; t < 2048; t += 1024) {
                    int i = ((t & ~(j - 1)) << 1) | (t & (j - 1));
                    int ip = i | j;
                    bool up = (((T * 4096 + i) & k2) == 0);
                    unsigned long long A = tile[i], B = tile[ip];
                    if ((A > B) == up) { tile[i] = B; tile[ip] = A; }
                }
                __syncthreads();
            }
            for (int t = tid; t < 4096; t += 1024) sortbuf[T * 4096 + t] = tile[t];
            __syncthreads();
        }
    };
    gstage(8192, 4096);  ltail(8192);
    gstage(16384, 8192); gstage(16384, 4096); ltail(16384);

    if (tid < NW) suppr[tid] = (tid == NW - 1) ? 0xFFFFFFFF00000000ULL : 0ULL;
    __syncthreads();
    for (int r = tid; r < NPRE_PAD; r += 1024) {
        float b0 = 0, b1 = 0, b2 = 0, b3 = 0;
        if (r < NPRE) {
            unsigned int idx = (unsigned int)(sortbuf[r] & 0xFFFFULL);
            const float* bp = boxes_all + (size_t)idx * 4;
            b0 = bp[0]; b1 = bp[1]; b2 = bp[2]; b3 = bp[3];
        }
        sbox[r * 4 + 0] = b0; sbox[r * 4 + 1] = b1;
        sbox[r * 4 + 2] = b2; sbox[r * 4 + 3] = b3;
        areas[r] = (b2 - b0) * (b3 - b1);
        if (r < NPRE) {
            bool valid = ((b2 - b0) >= 16.0f) && ((b3 - b1) >= 16.0f);
            if (!valid) atomicOr(&suppr[r >> 6], 1ULL << (r & 63));
        }
    }
}

// ---------------------------------------------------------------------------
// K4: pairwise IoU bit mask, upper-triangle layout. Grid (188, 4) x 256 thr:
// block = (cj, quarter of ci range); cj boxes cached in LDS, reused across
// all ci rows (was: 17766 single-wave blocks).
// ---------------------------------------------------------------------------
__global__ __launch_bounds__(256, 1)
void k_mask(const float* __restrict__ sbox, const float* __restrict__ areas,
            unsigned long long* __restrict__ mask)
{
    const int cj = blockIdx.x, q = blockIdx.y;
    __shared__ float4 bx[64];
    __shared__ float aj[64];
    const int t = threadIdx.x;
    const int j0 = cj * 64;
    if (t < 64) { bx[t] = ((const float4*)sbox)[j0 + t]; aj[t] = areas[j0 + t]; }
    __syncthreads();
    const int c0 = ((cj + 1) * q) >> 2, c1 = ((cj + 1) * (q + 1)) >> 2;
    for (int i0 = c0 * 64; i0 < c1 * 64; i0 += 256) {
        int i = i0 + t;
        if (i < c1 * 64) {
            const float4 p = ((const float4*)sbox)[i];
            const float ai = areas[i];
            unsigned long long w = 0;
            for (int jj = 0; jj < 64; ++jj) {
                float4 qb = bx[jj];
                float yy1 = fmaxf(p.x, qb.x), xx1 = fmaxf(p.y, qb.y);
                float yy2 = fminf(p.z, qb.z), xx2 = fminf(p.w, qb.w);
                float inter = fmaxf(yy2 - yy1, 0.f) * fmaxf(xx2 - xx1, 0.f);
                float iou = inter / (ai + aj[jj] - inter + 1e-10f);
                w |= ((unsigned long long)((iou > 0.7f) && (j0 + jj > i))) << jj;
            }
            int ci = i >> 6;
            mask[(size_t)(tribase(ci) + (cj - ci)) * 64 + (i & 63)] = w;
        }
    }
}

// ---------------------------------------------------------------------------
// K5: sequential greedy scan; rvs[] in LDS, 2 barriers/chunk.
// ---------------------------------------------------------------------------
__global__ __launch_bounds__(256, 1)
void k_scan(const unsigned long long* __restrict__ mask,
            const unsigned long long* __restrict__ suppr,
            const float* __restrict__ sbox, float* __restrict__ rois)
{
    __shared__ unsigned long long rvs[NW];
    __shared__ unsigned long long curw;
    __shared__ unsigned long long keptw[NW];
    __shared__ int totkept, brk;
    __shared__ int pref[NW + 1];
    const int tid = threadIdx.x;
    if (tid < NW) { rvs[tid] = suppr[tid]; keptw[tid] = 0ULL; }
    if (tid == 0) { totkept = 0; brk = 0; }
    __syncthreads();
    for (int c = 0; c < NW; ++c) {
        if (tid < 64) {  // wave-serial intra-chunk resolve (diag block of chunk c)
            unsigned long long diag = mask[(size_t)tribase(c) * 64 + tid];
            unsigned long long w = rvs[c];
            for (int b = 0; b < 64; ++b) {
                unsigned long long db = __shfl(diag, b, 64);
                if (!((w >> b) & 1ULL)) w |= db;
            }
            if (tid == 0) {
                curw = w;
                keptw[c] = ~w;
                totkept += __popcll(~w);
                if (totkept >= NPOST) brk = 1;
            }
        }
        __syncthreads();
        if (brk) break;
        unsigned long long kw = ~curw;
        if (tid > c && tid < NW) {  // apply kept rows of chunk c to future word tid
            const unsigned long long* mrow = mask + (size_t)(tribase(c) + (tid - c)) * 64;
            unsigned long long a0 = 0, a1 = 0, a2 = 0, a3 = 0;
            for (int b = 0; b < 64; b += 4) {
                unsigned long long m0 = mrow[b + 0];
                unsigned long long m1 = mrow[b + 1];
                unsigned long long m2 = mrow[b + 2];
                unsigned long long m3 = mrow[b + 3];
                if ((kw >> (b + 0)) & 1ULL) a0 |= m0;
                if ((kw >> (b + 1)) & 1ULL) a1 |= m1;
                if ((kw >> (b + 2)) & 1ULL) a2 |= m2;
                if ((kw >> (b + 3)) & 1ULL) a3 |= m3;
            }
            rvs[tid] |= a0 | a1 | a2 | a3;
        }
        __syncthreads();
    }
    __syncthreads();
    if (tid == 0) {
        int s = 0;
        for (int c = 0; c < NW; ++c) { pref[c] = s; s += __popcll(keptw[c]); }
        pref[NW] = s;
    }
    __syncthreads();
    int total = pref[NW]; if (total > NPOST) total = NPOST;
    for (int r = total * 4 + tid; r < NPOST * 4; r += 256) rois[r] = 0.f;
    if (tid < NW) {
        unsigned long long kw = keptw[tid];
        int r = pref[tid];
        for (int b = 0; b < 64; ++b) {
            if ((kw >> b) & 1ULL) {
                if (r < NPOST) {
                    const float* bp = sbox + (size_t)(tid * 64 + b) * 4;
                    rois[r * 4 + 0] = bp[0]; rois[r * 4 + 1] = bp[1];
                    rois[r * 4 + 2] = bp[2]; rois[r * 4 + 3] = bp[3];
                }
                ++r;
            }
        }
    }
}

// ---------------------------------------------------------------------------
extern "C" void kernel_launch(void* const* d_in, const int* in_sizes, int n_in,
                              void* d_out, int out_size, void* d_ws, size_t ws_size,
                              hipStream_t stream)
{
    const float* x       = (const float*)d_in[0];
    const float* conv_w  = (const float*)d_in[1];
    const float* conv_b  = (const float*)d_in[2];
    const float* score_w = (const float*)d_in[3];
    const float* score_b = (const float*)d_in[4];
    const float* loc_w   = (const float*)d_in[5];
    const float* loc_b   = (const float*)d_in[6];
    const int*   imh     = (const int*)d_in[7];
    const int*   imw     = (const int*)d_in[8];
    float* out = (float*)d_out;
    char* ws = (char*)d_ws;
    float* h                    = (float*)(ws);                         // 8388608
    float* boxes_all            = (float*)(ws + 8388608);               // 589824
    unsigned long long* keys64  = (unsigned long long*)(ws + 8978432);  // 294912
    float* sbox                 = (float*)(ws + 9273344);               // 192512
    float* areas                = (float*)(ws + 9465856);               // 48128
    unsigned long long* suppr   = (unsigned long long*)(ws + 9513984);  // 1536
    unsigned long long* sortbuf = (unsigned long long*)(ws + 9515520);  // 131072
    unsigned long long* mask    = (unsigned long long*)(ws + 9646592);  // 9096192

    k_conv  <<<512, 256, 0, stream>>>(x, conv_w, conv_b, h);
    k_heads <<<64, 256, 0, stream>>>(h, loc_w, loc_b, score_w, score_b, imh, imw,
                                     out, boxes_all, keys64);
    k_select<<<1, 1024, 0, stream>>>(keys64, boxes_all, sortbuf, sbox, areas, suppr);
    k_mask  <<<dim3(188, 4), 256, 0, stream>>>(sbox, areas, mask);
    k_scan  <<<1, 256, 0, stream>>>(mask, suppr, sbox, out + 221184);
}

// Round 5
// 1861.190 us; speedup vs baseline: 1.3549x; 1.3549x over previous
//
#include <hip/hip_runtime.h>
#include <cstdint>
#include <cstddef>
#include <math.h>

#define NANCH    36864
#define NPRE     12000
#define NPRE_PAD 12032
#define NW       188
#define SORT_N   16384
#define NPOST    2000

__device__ __forceinline__ int tribase(int ci) { return ci * NW - (ci * (ci - 1)) / 2; }

// ---------------------------------------------------------------------------
// K1a: K-split 3x3 conv half (512 ic), f64 partial accumulate, NO bias/relu.
// Grid 512 = 2 ksplits x (8 oc-tiles x 32 row-pairs); tile 64oc x 128px,
// micro 4oc x 8px (R3 shape: 4608 dfma/thread/chunk — R4's thin tile regressed).
// 2 blocks/CU co-resident (LDS 55KB): one block's barrier drain overlaps the
// other's dfma issue. Address math hoisted out of the k-loop.
// ---------------------------------------------------------------------------
__global__ __launch_bounds__(256, 2)
void k_conv_ks(const float* __restrict__ xg, const float* __restrict__ wg_,
               double* __restrict__ p0g, double* __restrict__ p1g)
{
    __shared__ float wlds[144 * 64];     // 36 KB
    __shared__ float xlds[16 * 4 * 76];  // 19 KB
    const int tid = threadIdx.x;
    const int ks  = blockIdx.x >> 8;         // 0/1 k-half
    const int inner = blockIdx.x & 255;
    const int oct = inner & 7;
    const int rp  = inner >> 3;              // 0..31
    const int oc0 = oct << 6;
    const int y0  = rp << 1;
    const int ocg = tid >> 4;
    const int pxg = tid & 15;
    const int ry  = pxg >> 3;
    const int cx0 = (pxg & 7) << 3;
    const int lane = tid & 63, wv = tid >> 6;
    const int icbase = ks << 9;              // 0 or 512

    double acc[4][8];
#pragma unroll
    for (int o = 0; o < 4; ++o)
#pragma unroll
        for (int j = 0; j < 8; ++j) acc[o][j] = 0.0;

    // hoisted staging address math (was recomputed every chunk in R3/R4)
    int xoff[17], loff[17];
#pragma unroll
    for (int t = 0; t < 17; ++t) {
        int f = tid + 256 * t;
        if (f < 4224) {
            int ic = f / 264; int r = f - ic * 264; int srow = r / 66; int gc = r - srow * 66;
            loff[t] = (ic * 4 + srow) * 76 + gc;
            int gy = y0 + srow - 1, gx = gc - 1;
            xoff[t] = (gy >= 0 && gy < 64 && gx >= 0 && gx < 64)
                      ? (ic * 4096 + gy * 64 + gx) : -1;
        } else { loff[t] = -1; xoff[t] = -1; }
    }

    const float* wbase = wg_ + (size_t)(oc0 + lane) * 9216 + (size_t)icbase * 9 + wv;
    const float* xbase = xg + (size_t)icbase * 4096;
    float wreg[36], xreg[17];

    // prologue
#pragma unroll
    for (int t = 0; t < 36; ++t) wreg[t] = wbase[4 * t];
#pragma unroll
    for (int t = 0; t < 17; ++t) xreg[t] = (xoff[t] >= 0) ? xbase[xoff[t]] : 0.f;

    for (int kc = 0; kc < 32; ++kc) {
        __syncthreads();
#pragma unroll
        for (int t = 0; t < 36; ++t) wlds[(wv + 4 * t) * 64 + lane] = wreg[t];
#pragma unroll
        for (int t = 0; t < 17; ++t)
            if (loff[t] >= 0) xlds[loff[t]] = xreg[t];
        if (kc < 31) {
            const float* wp = wbase + (kc + 1) * 144;
            const float* xp = xbase + (size_t)(kc + 1) * 16 * 4096;
#pragma unroll
            for (int t = 0; t < 36; ++t) wreg[t] = wp[4 * t];
#pragma unroll
            for (int t = 0; t < 17; ++t) xreg[t] = (xoff[t] >= 0) ? xp[xoff[t]] : 0.f;
        }
        __syncthreads();
#pragma unroll 1
        for (int ic = 0; ic < 16; ++ic) {
#pragma unroll
            for (int ky = 0; ky < 3; ++ky) {
                const float* xr = &xlds[(ic * 4 + ry + ky) * 76 + cx0];
                float4 t0 = *(const float4*)(xr);
                float4 t1 = *(const float4*)(xr + 4);
                float2 t2 = *(const float2*)(xr + 8);
                double xwd[10] = {t0.x, t0.y, t0.z, t0.w, t1.x, t1.y, t1.z, t1.w, t2.x, t2.y};
#pragma unroll
                for (int kx = 0; kx < 3; ++kx) {
                    const float4 wq = *(const float4*)&wlds[(ic * 9 + ky * 3 + kx) * 64 + (ocg << 2)];
                    double wdv[4] = {wq.x, wq.y, wq.z, wq.w};
#pragma unroll
                    for (int o = 0; o < 4; ++o)
#pragma unroll
                        for (int j = 0; j < 8; ++j)
                            acc[o][j] = fma(wdv[o], xwd[j + kx], acc[o][j]);
                }
            }
        }
    }
    double* pg = ks ? p1g : p0g;
#pragma unroll
    for (int o = 0; o < 4; ++o) {
        const int oc = oc0 + (ocg << 2) + o;
        double* pp = pg + (size_t)oc * 4096 + (y0 + ry) * 64 + cx0;
#pragma unroll
        for (int j = 0; j < 8; j += 2)
            *(double2*)(pp + j) = make_double2(acc[o][j], acc[o][j + 1]);
    }
}

// K1b: combine halves + bias + leaky, cast f32 (sum0+sum1+bias: rank-safe)
__global__ __launch_bounds__(256, 4)
void k_comb(const double* __restrict__ p0, const double* __restrict__ p1,
            const float* __restrict__ bg, float* __restrict__ hg)
{
    int i2 = (blockIdx.x * 256 + threadIdx.x) * 2;
    double2 a = *(const double2*)(p0 + i2);
    double2 b = *(const double2*)(p1 + i2);
    double bo = (double)bg[i2 >> 12];
    double t0 = a.x + b.x + bo, t1 = a.y + b.y + bo;
    float v0 = (float)((t0 >= 0.0) ? t0 : 0.01 * t0);
    float v1 = (float)((t1 >= 0.0) ? t1 : 0.01 * t1);
    *(float2*)(hg + i2) = make_float2(v0, v1);
}

// ---------------------------------------------------------------------------
// K1-fallback: R3 full conv (grid 256), used only if ws_size < 40MB.
// ---------------------------------------------------------------------------
__global__ __launch_bounds__(256, 1)
void k_conv_full(const float* __restrict__ xg, const float* __restrict__ wg_,
                 const float* __restrict__ bg, float* __restrict__ hg)
{
    __shared__ float wlds[144 * 64];
    __shared__ float xlds[16 * 4 * 76];
    const int tid = threadIdx.x;
    const int oct = blockIdx.x & 7;
    const int rp  = blockIdx.x >> 3;
    const int oc0 = oct << 6;
    const int y0  = rp << 1;
    const int ocg = tid >> 4;
    const int pxg = tid & 15;
    const int ry  = pxg >> 3;
    const int cx0 = (pxg & 7) << 3;
    const int lane = tid & 63, wv = tid >> 6;
    double acc[4][8];
#pragma unroll
    for (int o = 0; o < 4; ++o)
#pragma unroll
        for (int j = 0; j < 8; ++j) acc[o][j] = 0.0;
    int xoff[17], loff[17];
#pragma unroll
    for (int t = 0; t < 17; ++t) {
        int f = tid + 256 * t;
        if (f < 4224) {
            int ic = f / 264; int r = f - ic * 264; int srow = r / 66; int gc = r - srow * 66;
            loff[t] = (ic * 4 + srow) * 76 + gc;
            int gy = y0 + srow - 1, gx = gc - 1;
            xoff[t] = (gy >= 0 && gy < 64 && gx >= 0 && gx < 64)
                      ? (ic * 4096 + gy * 64 + gx) : -1;
        } else { loff[t] = -1; xoff[t] = -1; }
    }
    const float* wbase = wg_ + (size_t)(oc0 + lane) * 9216 + wv;
    float wreg[36], xreg[17];
#pragma unroll
    for (int t = 0; t < 36; ++t) wreg[t] = wbase[4 * t];
#pragma unroll
    for (int t = 0; t < 17; ++t) xreg[t] = (xoff[t] >= 0) ? xg[xoff[t]] : 0.f;
    for (int kc = 0; kc < 64; ++kc) {
        __syncthreads();
#pragma unroll
        for (int t = 0; t < 36; ++t) wlds[(wv + 4 * t) * 64 + lane] = wreg[t];
#pragma unroll
        for (int t = 0; t < 17; ++t)
            if (loff[t] >= 0) xlds[loff[t]] = xreg[t];
        if (kc < 63) {
            const float* wp = wbase + (kc + 1) * 144;
            const float* xp = xg + (size_t)(kc + 1) * 16 * 4096;
#pragma unroll
            for (int t = 0; t < 36; ++t) wreg[t] = wp[4 * t];
#pragma unroll
            for (int t = 0; t < 17; ++t) xreg[t] = (xoff[t] >= 0) ? xp[xoff[t]] : 0.f;
        }
        __syncthreads();
#pragma unroll 1
        for (int ic = 0; ic < 16; ++ic) {
#pragma unroll
            for (int ky = 0; ky < 3; ++ky) {
                const float* xr = &xlds[(ic * 4 + ry + ky) * 76 + cx0];
                float4 t0 = *(const float4*)(xr);
                float4 t1 = *(const float4*)(xr + 4);
                float2 t2 = *(const float2*)(xr + 8);
                double xwd[10] = {t0.x, t0.y, t0.z, t0.w, t1.x, t1.y, t1.z, t1.w, t2.x, t2.y};
#pragma unroll
                for (int kx = 0; kx < 3; ++kx) {
                    const float4 wq = *(const float4*)&wlds[(ic * 9 + ky * 3 + kx) * 64 + (ocg << 2)];
                    double wdv[4] = {wq.x, wq.y, wq.z, wq.w};
#pragma unroll
                    for (int o = 0; o < 4; ++o)
#pragma unroll
                        for (int j = 0; j < 8; ++j)
                            acc[o][j] = fma(wdv[o], xwd[j + kx], acc[o][j]);
                }
            }
        }
    }
#pragma unroll
    for (int o = 0; o < 4; ++o) {
        const int oc = oc0 + (ocg << 2) + o;
        const double bo = (double)bg[oc];
        float* hp = hg + (size_t)oc * 4096 + (y0 + ry) * 64 + cx0;
        float v[8];
#pragma unroll
        for (int j = 0; j < 8; ++j) {
            double t = acc[o][j] + bo;
            v[j] = (float)((t >= 0.0) ? t : 0.01 * t);
        }
        *(float4*)(hp)     = make_float4(v[0], v[1], v[2], v[3]);
        *(float4*)(hp + 4) = make_float4(v[4], v[5], v[6], v[7]);
    }
}

// ---------------------------------------------------------------------------
// K2: 1x1 convs (f64 accumulate) + f64 sort keys + anchors + f32 box deparam
// ---------------------------------------------------------------------------
__global__ __launch_bounds__(256, 1)
void k_heads(const float* __restrict__ hg, const float* __restrict__ loc_w,
             const float* __restrict__ loc_b, const float* __restrict__ score_w,
             const float* __restrict__ score_b, const int* __restrict__ imh,
             const int* __restrict__ imw, float* __restrict__ out,
             float* __restrict__ boxes_all, unsigned long long* __restrict__ keys64)
{
    __shared__ float  hch[64 * 64];
    __shared__ float  wch[54 * 64];
    __shared__ float  ol[54 * 64];
    __shared__ double sld[18 * 64];
    const int y = blockIdx.x, tid = threadIdx.x;
    const int px = tid & 63, cg = tid >> 6;
    double acc[14];
#pragma unroll
    for (int u = 0; u < 14; ++u) acc[u] = 0.0;
    for (int cc = 0; cc < 8; ++cc) {
        __syncthreads();
#pragma unroll
        for (int t = 0; t < 16; ++t) {
            int f = tid + 256 * t;
            hch[f] = hg[(size_t)(cc * 64 + (f >> 6)) * 4096 + y * 64 + (f & 63)];
        }
#pragma unroll
        for (int t = 0; t < 14; ++t) {
            int f = tid + 256 * t;
            if (f < 54 * 64) {
                int ch = f >> 6, c = f & 63;
                wch[f] = (ch < 36) ? loc_w[ch * 512 + cc * 64 + c]
                                   : score_w[(ch - 36) * 512 + cc * 64 + c];
            }
        }
        __syncthreads();
        for (int c = 0; c < 64; ++c) {
            double hvd = (double)hch[c * 64 + px];
#pragma unroll
            for (int u = 0; u < 14; ++u) {
                int ch = cg + 4 * u;
                if (ch < 54) acc[u] = fma((double)wch[ch * 64 + c], hvd, acc[u]);
            }
        }
    }
    __syncthreads();
#pragma unroll
    for (int u = 0; u < 14; ++u) {
        int ch = cg + 4 * u;
        if (ch < 54) {
            double s = acc[u] + (double)((ch < 36) ? loc_b[ch] : score_b[ch - 36]);
            ol[ch * 64 + px] = (float)s;
            if (ch >= 36) sld[(ch - 36) * 64 + px] = s;
        }
    }
    __syncthreads();
    for (int f = tid; f < 64 * 36; f += 256) {
        int p = f / 36, ch = f - 36 * p;
        out[(size_t)(y * 64 + p) * 36 + ch] = ol[ch * 64 + p];
    }
    for (int f = tid; f < 64 * 18; f += 256) {
        int p = f / 18, ch = f - 18 * p;
        out[147456 + (size_t)(y * 64 + p) * 18 + ch] = ol[(36 + ch) * 64 + p];
    }
    const float fy = (float)(*imh), fx = (float)(*imw);
    float* anch = out + 229184;
    for (int t2 = tid; t2 < 576; t2 += 256) {
        int p = t2 / 9, a = t2 - 9 * p;
        int pg = y * 64 + p;
        int ar = a / 3, as = a - 3 * ar;
        double rr = (ar == 0) ? 0.5 : ((ar == 1) ? 1.0 : 2.0);
        double ss = (as == 0) ? 8.0 : ((as == 1) ? 16.0 : 32.0);
        double hh = 16.0 * ss * sqrt(rr), wwd = 16.0 * ss * sqrt(1.0 / rr);
        float by1 = (float)(8.0 - hh * 0.5), bx1 = (float)(8.0 - wwd * 0.5);
        float by2 = (float)(8.0 + hh * 0.5), bx2 = (float)(8.0 + wwd * 0.5);
        float sy = (float)(y * 16), sx = (float)(p * 16);
        float a0 = sy + by1, a1 = sx + bx1, a2 = sy + by2, a3 = sx + bx2;
        int base = (pg * 9 + a) * 4;
        anch[base + 0] = a0; anch[base + 1] = a1; anch[base + 2] = a2; anch[base + 3] = a3;
        double d = sld[(a * 2 + 1) * 64 + p] - sld[(a * 2) * 64 + p];
        long long bits = __double_as_longlong(d);
        unsigned long long u64 =
            (unsigned long long)(bits ^ ((bits >> 63) | (long long)0x8000000000000000LL));
        unsigned long long v = ~u64;
        keys64[pg * 9 + a] = (v & 0xFFFFFFFFFFFF0000ULL) | (unsigned long long)(pg * 9 + a);
        float dy = ol[(a * 4 + 0) * 64 + p], dxv = ol[(a * 4 + 1) * 64 + p];
        float dh = ol[(a * 4 + 2) * 64 + p], dwv = ol[(a * 4 + 3) * 64 + p];
        float hA = a2 - a0, wA = a3 - a1;
        float cya = a0 + 0.5f * hA, cxa = a1 + 0.5f * wA;
        float cy = dy * hA + cya, cx = dxv * wA + cxa;
        float hb = hA * expf(dh), wb = wA * expf(dwv);
        float b0 = fminf(fmaxf(cy - 0.5f * hb, 0.f), fy);
        float b1 = fminf(fmaxf(cx - 0.5f * wb, 0.f), fx);
        float b2 = fminf(fmaxf(cy + 0.5f * hb, 0.f), fy);
        float b3 = fminf(fmaxf(cx + 0.5f * wb, 0.f), fx);
        boxes_all[base + 0] = b0; boxes_all[base + 1] = b1;
        boxes_all[base + 2] = b2; boxes_all[base + 3] = b3;
    }
}

// ---------------------------------------------------------------------------
// K3: radix-select 12000 smallest, compact, LDS-tiled bitonic sort.
// ---------------------------------------------------------------------------
__global__ __launch_bounds__(1024, 1)
void k_select(const unsigned long long* __restrict__ keys64,
              const float* __restrict__ boxes_all,
              unsigned long long* __restrict__ sortbuf, float* __restrict__ sbox,
              float* __restrict__ areas, unsigned long long* __restrict__ suppr)
{
    __shared__ unsigned int hist[256];
    __shared__ unsigned int sh_below, sh_prefix, sh_nsel;
    __shared__ unsigned long long tile[4096];
    const int tid = threadIdx.x;
    if (tid == 0) { sh_below = 0; sh_prefix = 0; sh_nsel = 0; }
    __syncthreads();
    for (int p = 3; p >= 0; --p) {
        if (tid < 256) hist[tid] = 0;
        __syncthreads();
        unsigned int pref = sh_prefix;
        int shift = p * 8;
        for (int i = tid; i < NANCH; i += 1024) {
            unsigned int k = (unsigned int)(keys64[i] >> 32);
            bool match = (p == 3) || ((k >> (shift + 8)) == pref);
            if (match) atomicAdd(&hist[(k >> shift) & 255u], 1u);
        }
        __syncthreads();
        if (tid == 0) {
            unsigned int below = sh_below, cacc = 0;
            int b = 0;
            for (; b < 256; ++b) {
                if (below + cacc + hist[b] >= NPRE) break;
                cacc += hist[b];
            }
            if (b > 255) b = 255;
            sh_below = below + cacc;
            sh_prefix = (pref << 8) | (unsigned int)b;
        }
        __syncthreads();
    }
    const unsigned int P = sh_prefix;
    for (int i = tid; i < NANCH; i += 1024) {
        unsigned long long k = keys64[i];
        if ((unsigned int)(k >> 32) <= P) {
            unsigned int pos = atomicAdd(&sh_nsel, 1u);
            if (pos < SORT_N) sortbuf[pos] = k;
        }
    }
    __syncthreads();
    unsigned int nsel = sh_nsel; if (nsel > SORT_N) nsel = SORT_N;
    for (unsigned int i = nsel + tid; i < SORT_N; i += 1024) sortbuf[i] = ~0ULL;
    __syncthreads();
    for (int T = 0; T < 4; ++T) {
        for (int t = tid; t < 4096; t += 1024) tile[t] = sortbuf[T * 4096 + t];
        __syncthreads();
        for (int k2 = 2; k2 <= 4096; k2 <<= 1) {
            for (int j = k2 >> 1; j > 0; j >>= 1) {
                for (int t = tid; t < 2048; t += 1024) {
                    int i = ((t & ~(j - 1)) << 1) | (t & (j - 1));
                    int ip = i | j;
                    bool up = (((T * 4096 + i) & k2) == 0);
                    unsigned long long A = tile[i], B = tile[ip];
                    if ((A > B) == up) { tile[i] = B; tile[ip] = A; }
                }
                __syncthreads();
            }
        }
        for (int t = tid; t < 4096; t += 1024) sortbuf[T * 4096 + t] = tile[t];
        __syncthreads();
    }
    auto gstage = [&](int k2, int j) {
        for (int t = tid; t < 8192; t += 1024) {
            int i = ((t & ~(j - 1)) << 1) | (t & (j - 1));
            int ip = i | j;
            bool up = ((i & k2) == 0);
            unsigned long long A = sortbuf[i], B = sortbuf[ip];
            if ((A > B) == up) { sortbuf[i] = B; sortbuf[ip] = A; }
        }
        __syncthreads();
    };
    auto ltail = [&](int k2) {
        for (int T = 0; T < 4; ++T) {
            for (int t = tid; t < 4096; t += 1024) tile[t] = sortbuf[T * 4096 + t];
            __syncthreads();
            for (int j = 2048; j > 0; j >>= 1) {
                for (int t = tid; t < 2048; t += 1024) {
                    int i = ((t & ~(j - 1)) << 1) | (t & (j - 1));
                    int ip = i | j;
                    bool up = (((T * 4096 + i) & k2) == 0);
                    unsigned long long A = tile[i], B = tile[ip];
                    if ((A > B) == up) { tile[i] = B; tile[ip] = A; }
                }
                __syncthreads();
            }
            for (int t = tid; t < 4096; t += 1024) sortbuf[T * 4096 + t] = tile[t];
            __syncthreads();
        }
    };
    gstage(8192, 4096);  ltail(8192);
    gstage(16384, 8192); gstage(16384, 4096); ltail(16384);

    if (tid < NW) suppr[tid] = (tid == NW - 1) ? 0xFFFFFFFF00000000ULL : 0ULL;
    __syncthreads();
    for (int r = tid; r < NPRE_PAD; r += 1024) {
        float b0 = 0, b1 = 0, b2 = 0, b3 = 0;
        if (r < NPRE) {
            unsigned int idx = (unsigned int)(sortbuf[r] & 0xFFFFULL);
            const float* bp = boxes_all + (size_t)idx * 4;
            b0 = bp[0]; b1 = bp[1]; b2 = bp[2]; b3 = bp[3];
        }
        sbox[r * 4 + 0] = b0; sbox[r * 4 + 1] = b1;
        sbox[r * 4 + 2] = b2; sbox[r * 4 + 3] = b3;
        areas[r] = (b2 - b0) * (b3 - b1);
        if (r < NPRE) {
            bool valid = ((b2 - b0) >= 16.0f) && ((b3 - b1) >= 16.0f);
            if (!valid) atomicOr(&suppr[r >> 6], 1ULL << (r & 63));
        }
    }
}

// ---------------------------------------------------------------------------
// K4: pairwise IoU bit mask, upper-triangle layout. Grid (188,4) x 256 thr.
// ---------------------------------------------------------------------------
__global__ __launch_bounds__(256, 1)
void k_mask(const float* __restrict__ sbox, const float* __restrict__ areas,
            unsigned long long* __restrict__ mask)
{
    const int cj = blockIdx.x, q = blockIdx.y;
    __shared__ float4 bx[64];
    __shared__ float aj[64];
    const int t = threadIdx.x;
    const int j0 = cj * 64;
    if (t < 64) { bx[t] = ((const float4*)sbox)[j0 + t]; aj[t] = areas[j0 + t]; }
    __syncthreads();
    const int c0 = ((cj + 1) * q) >> 2, c1 = ((cj + 1) * (q + 1)) >> 2;
    for (int i0 = c0 * 64; i0 < c1 * 64; i0 += 256) {
        int i = i0 + t;
        if (i < c1 * 64) {
            const float4 p = ((const float4*)sbox)[i];
            const float ai = areas[i];
            unsigned long long w = 0;
            for (int jj = 0; jj < 64; ++jj) {
                float4 qb = bx[jj];
                float yy1 = fmaxf(p.x, qb.x), xx1 = fmaxf(p.y, qb.y);
                float yy2 = fminf(p.z, qb.z), xx2 = fminf(p.w, qb.w);
                float inter = fmaxf(yy2 - yy1, 0.f) * fmaxf(xx2 - xx1, 0.f);
                float iou = inter / (ai + aj[jj] - inter + 1e-10f);
                w |= ((unsigned long long)((iou > 0.7f) && (j0 + jj > i))) << jj;
            }
            int ci = i >> 6;
            mask[(size_t)(tribase(ci) + (cj - ci)) * 64 + (i & 63)] = w;
        }
    }
}

// ---------------------------------------------------------------------------
// K5: sequential greedy scan; rvs[] in LDS, early exit at 2000 kept.
// ---------------------------------------------------------------------------
__global__ __launch_bounds__(256, 1)
void k_scan(const unsigned long long* __restrict__ mask,
            const unsigned long long* __restrict__ suppr,
            const float* __restrict__ sbox, float* __restrict__ rois)
{
    __shared__ unsigned long long rvs[NW];
    __shared__ unsigned long long curw;
    __shared__ unsigned long long keptw[NW];
    __shared__ int totkept, brk;
    __shared__ int pref[NW + 1];
    const int tid = threadIdx.x;
    if (tid < NW) { rvs[tid] = suppr[tid]; keptw[tid] = 0ULL; }
    if (tid == 0) { totkept = 0; brk = 0; }
    __syncthreads();
    for (int c = 0; c < NW; ++c) {
        if (tid < 64) {
            unsigned long long diag = mask[(size_t)tribase(c) * 64 + tid];
            unsigned long long w = rvs[c];
            for (int b = 0; b < 64; ++b) {
                unsigned long long db = __shfl(diag, b, 64);
                if (!((w >> b) & 1ULL)) w |= db;
            }
            if (tid == 0) {
                curw = w;
                keptw[c] = ~w;
                totkept += __popcll(~w);
                if (totkept >= NPOST) brk = 1;
            }
        }
        __syncthreads();
        if (brk) break;
        unsigned long long kw = ~curw;
        if (tid > c && tid < NW) {
            const unsigned long long* mrow = mask + (size_t)(tribase(c) + (tid - c)) * 64;
            unsigned long long a0 = 0, a1 = 0, a2 = 0, a3 = 0;
            for (int b = 0; b < 64; b += 4) {
                unsigned long long m0 = mrow[b + 0];
                unsigned long long m1 = mrow[b + 1];
                unsigned long long m2 = mrow[b + 2];
                unsigned long long m3 = mrow[b + 3];
                if ((kw >> (b + 0)) & 1ULL) a0 |= m0;
                if ((kw >> (b + 1)) & 1ULL) a1 |= m1;
                if ((kw >> (b + 2)) & 1ULL) a2 |= m2;
                if ((kw >> (b + 3)) & 1ULL) a3 |= m3;
            }
            rvs[tid] |= a0 | a1 | a2 | a3;
        }
        __syncthreads();
    }
    __syncthreads();
    if (tid == 0) {
        int s = 0;
        for (int c = 0; c < NW; ++c) { pref[c] = s; s += __popcll(keptw[c]); }
        pref[NW] = s;
    }
    __syncthreads();
    int total = pref[NW]; if (total > NPOST) total = NPOST;
    for (int r = total * 4 + tid; r < NPOST * 4; r += 256) rois[r] = 0.f;
    if (tid < NW) {
        unsigned long long kw = keptw[tid];
        int r = pref[tid];
        for (int b = 0; b < 64; ++b) {
            if ((kw >> b) & 1ULL) {
                if (r < NPOST) {
                    const float* bp = sbox + (size_t)(tid * 64 + b) * 4;
                    rois[r * 4 + 0] = bp[0]; rois[r * 4 + 1] = bp[1];
                    rois[r * 4 + 2] = bp[2]; rois[r * 4 + 3] = bp[3];
                }
                ++r;
            }
        }
    }
}

// ---------------------------------------------------------------------------
extern "C" void kernel_launch(void* const* d_in, const int* in_sizes, int n_in,
                              void* d_out, int out_size, void* d_ws, size_t ws_size,
                              hipStream_t stream)
{
    const float* x       = (const float*)d_in[0];
    const float* conv_w  = (const float*)d_in[1];
    const float* conv_b  = (const float*)d_in[2];
    const float* score_w = (const float*)d_in[3];
    const float* score_b = (const float*)d_in[4];
    const float* loc_w   = (const float*)d_in[5];
    const float* loc_b   = (const float*)d_in[6];
    const int*   imh     = (const int*)d_in[7];
    const int*   imw     = (const int*)d_in[8];
    float* out = (float*)d_out;
    char* ws = (char*)d_ws;
    // layout: [h 8.4MB][P0 16.8MB][P1 16.8MB]; tail buffers overlay P0/P1
    // (partials die at k_comb, before boxes/keys/mask are written). 40MB total.
    float* h                    = (float*)(ws);                         // 8388608
    double* P0                  = (double*)(ws + 8388608);              // 16777216
    double* P1                  = (double*)(ws + 25165824);             // 16777216
    float* boxes_all            = (float*)(ws + 8388608);               // 589824
    unsigned long long* keys64  = (unsigned long long*)(ws + 8978432);  // 294912
    float* sbox                 = (float*)(ws + 9273344);               // 192512
    float* areas                = (float*)(ws + 9465856);               // 48128
    unsigned long long* suppr   = (unsigned long long*)(ws + 9513984);  // 1536
    unsigned long long* sortbuf = (unsigned long long*)(ws + 9515520);  // 131072
    unsigned long long* mask    = (unsigned long long*)(ws + 9646592);  // 9096192

    if (ws_size >= 41943040) {
        k_conv_ks<<<512, 256, 0, stream>>>(x, conv_w, P0, P1);
        k_comb   <<<4096, 256, 0, stream>>>(P0, P1, conv_b, h);
    } else {
        k_conv_full<<<256, 256, 0, stream>>>(x, conv_w, conv_b, h);
    }
    k_heads <<<64, 256, 0, stream>>>(h, loc_w, loc_b, score_w, score_b, imh, imw,
                                     out, boxes_all, keys64);
    k_select<<<1, 1024, 0, stream>>>(keys64, boxes_all, sortbuf, sbox, areas, suppr);
    k_mask  <<<dim3(188, 4), 256, 0, stream>>>(sbox, areas, mask);
    k_scan  <<<1, 256, 0, stream>>>(mask, suppr, sbox, out + 221184);
}